// Round 11
// baseline (345.032 us; speedup 1.0000x reference)
//
#include <hip/hip_runtime.h>

#define N_ROWS 131072
#define KCODES 1024
#define DIM 64
#define BLOCK 256
#define ROWS_PB 128
#define KCHUNK 128
#define NCHUNK (KCODES / KCHUNK)

// padded LDS row offset: row stride 68 floats + 4-float pad every 8 rows.
// 8-row group stride = 548 floats = 4 mod 32 banks.
__device__ __forceinline__ int POFF(int r) { return r * 68 + (r >> 3) * 4; }

// h: [32, 64, 64, 64] fp32 (B, D, H, W); codebook: [1024, 64] fp32
// out: z[131072] as float ++ q[131072*64] fp32 ; d_ws unused

__global__ void
__attribute__((amdgpu_flat_work_group_size(256, 256), amdgpu_waves_per_eu(2, 2)))
vq_main(const float* __restrict__ h,
        const float* __restrict__ cb,
        float* __restrict__ z_out,
        float* __restrict__ q_out)
{
    __shared__ __align__(16) float xs[8760];   // 128 rows, padded  (35040 B)
    __shared__ __align__(16) float cs[8760];   // 128 codes, padded (35040 B, reused for merge)
    __shared__ float s_c2[KCODES];             // 4096 B
    __shared__ float ss[ROWS_PB];              // 512 B
    __shared__ int   s_idx[ROWS_PB];           // 512 B

    const int tid  = threadIdx.x;
    const int row0 = blockIdx.x * ROWS_PB;
    const int bb   = row0 >> 12;
    const int yx0  = row0 & 4095;

    // ---- stage x tile (coalesced: lanes = consecutive rows) ----
    {
        const int rl = tid & 127;
        const int dg = tid >> 7;              // 0..1
        const float* hb = h + (size_t)bb * (DIM * 4096) + yx0 + rl;
        const int xo = POFF(rl);
#pragma unroll
        for (int t = 0; t < 32; ++t) {
            const int d = t * 2 + dg;
            xs[xo + d] = hb[(size_t)d * 4096];
        }
    }

    // ---- s_c2 for ALL codes, once, from global (bit-identical pairwise formula) ----
    {
#pragma clang fp contract(off)
#pragma unroll
        for (int cc = 0; cc < 4; ++cc) {
            const int code = cc * BLOCK + tid;
            const float* c = cb + code * DIM;
            float r0 = c[0]*c[0], r1 = c[1]*c[1], r2 = c[2]*c[2], r3 = c[3]*c[3];
            float r4 = c[4]*c[4], r5 = c[5]*c[5], r6 = c[6]*c[6], r7 = c[7]*c[7];
#pragma unroll
            for (int i = 1; i < 8; ++i) {
                r0 = r0 + c[i*8+0]*c[i*8+0];
                r1 = r1 + c[i*8+1]*c[i*8+1];
                r2 = r2 + c[i*8+2]*c[i*8+2];
                r3 = r3 + c[i*8+3]*c[i*8+3];
                r4 = r4 + c[i*8+4]*c[i*8+4];
                r5 = r5 + c[i*8+5]*c[i*8+5];
                r6 = r6 + c[i*8+6]*c[i*8+6];
                r7 = r7 + c[i*8+7]*c[i*8+7];
            }
            s_c2[code] = ((r0 + r1) + (r2 + r3)) + ((r4 + r5) + (r6 + r7));
        }
    }
    __syncthreads();

    // ---- S[r] = ||x_r||^2 from staged xs (same bits as global) ----
    if (tid < ROWS_PB) {
#pragma clang fp contract(off)
        const float* xr = &xs[POFF(tid)];
        float r0 = xr[0]*xr[0], r1 = xr[1]*xr[1], r2 = xr[2]*xr[2], r3 = xr[3]*xr[3];
        float r4 = xr[4]*xr[4], r5 = xr[5]*xr[5], r6 = xr[6]*xr[6], r7 = xr[7]*xr[7];
#pragma unroll
        for (int i = 1; i < 8; ++i) {
            r0 = r0 + xr[i*8+0]*xr[i*8+0];
            r1 = r1 + xr[i*8+1]*xr[i*8+1];
            r2 = r2 + xr[i*8+2]*xr[i*8+2];
            r3 = r3 + xr[i*8+3]*xr[i*8+3];
            r4 = r4 + xr[i*8+4]*xr[i*8+4];
            r5 = r5 + xr[i*8+5]*xr[i*8+5];
            r6 = r6 + xr[i*8+6]*xr[i*8+6];
            r7 = r7 + xr[i*8+7]*xr[i*8+7];
        }
        ss[tid] = ((r0 + r1) + (r2 + r3)) + ((r4 + r5) + (r6 + r7));
    }
    __syncthreads();

    // ---- thread tile 8x8 with 8x8 WITHIN-WAVE sub-grid ----
    // per wave-inst: cf reads 8 distinct addrs (bank-quads 0,4,..,28 -> all 32 banks
    // once, conflict-free, 8-lane broadcast); xf reads likewise.
    const int wave = tid >> 6;
    const int lane = tid & 63;
    const int rg   = (wave >> 1) * 8 + (lane >> 3);   // 0..15
    const int cg   = (wave & 1) * 8 + (lane & 7);     // 0..15
    const float* xb   = &xs[POFF(rg * 8)];   // row rr at +68*rr (no pad inside group)
    const float* cbse = &cs[POFF(cg * 8)];   // code j at +68*j

    float Sv[8];
#pragma unroll
    for (int rr = 0; rr < 8; ++rr) Sv[rr] = ss[rg * 8 + rr];

    float bd[8];
    int   bk[8];
#pragma unroll
    for (int rr = 0; rr < 8; ++rr) { bd[rr] = 3.4e38f; bk[rr] = 0; }

    for (int kc = 0; kc < NCHUNK; ++kc) {
        __syncthreads();                   // cs reuse guard
        {
            const float4* g4 = (const float4*)(cb + kc * KCHUNK * DIM);
#pragma unroll
            for (int i = 0; i < 8; ++i) {
                const int g    = i * BLOCK + tid;   // 0..2047
                const int code = g >> 4;
                const int col  = g & 15;
                *(float4*)&cs[POFF(code) + col * 4] = g4[g];
            }
        }
        __syncthreads();

        float acc[8][8];
#pragma unroll
        for (int rr = 0; rr < 8; ++rr)
#pragma unroll
            for (int j = 0; j < 8; ++j) acc[rr][j] = 0.0f;

#pragma unroll 2
        for (int dc = 0; dc < 16; ++dc) {
            const int d = dc * 4;
            float4 cf[8];
#pragma unroll
            for (int j = 0; j < 8; ++j)
                cf[j] = *(const float4*)&cbse[68 * j + d];
#pragma unroll
            for (int rr = 0; rr < 8; ++rr) {
                const float4 xf = *(const float4*)&xb[68 * rr + d];
#pragma unroll
                for (int j = 0; j < 8; ++j) {
                    acc[rr][j] = __builtin_fmaf(xf.x, cf[j].x, acc[rr][j]);
                    acc[rr][j] = __builtin_fmaf(xf.y, cf[j].y, acc[rr][j]);
                    acc[rr][j] = __builtin_fmaf(xf.z, cf[j].z, acc[rr][j]);
                    acc[rr][j] = __builtin_fmaf(xf.w, cf[j].w, acc[rr][j]);
                }
            }
        }

        // chunk epilogue: exact d2 + argmin, j ascending = k ascending
#pragma unroll
        for (int j = 0; j < 8; ++j) {
            {
#pragma clang fp contract(off)
                const int k     = kc * KCHUNK + cg * 8 + j;
                const float c2v = s_c2[k];
#pragma unroll
                for (int rr = 0; rr < 8; ++rr) {
                    float t  = 2.0f * acc[rr][j];   // exact
                    float u  = Sv[rr] - t;          // rounded like np
                    float d2 = u + c2v;
                    if (d2 < bd[rr]) { bd[rr] = d2; bk[rr] = k; }
                }
            }
        }
    }

    // ---- merge: per-row lex-min over 16 cg slots (d,k) = np first-index ----
    __syncthreads();
    float* sbd = cs;                          // [128][16]
    int*   sbk = (int*)(cs + ROWS_PB * 16);   // [128][16]
#pragma unroll
    for (int rr = 0; rr < 8; ++rr) {
        sbd[(rg * 8 + rr) * 16 + cg] = bd[rr];
        sbk[(rg * 8 + rr) * 16 + cg] = bk[rr];
    }
    __syncthreads();

    if (tid < ROWS_PB) {
        float fb = sbd[tid * 16];
        int   fk = sbk[tid * 16];
#pragma unroll
        for (int s = 1; s < 16; ++s) {
            const float d = sbd[tid * 16 + s];
            const int   k = sbk[tid * 16 + s];
            if (d < fb || (d == fb && k < fk)) { fb = d; fk = k; }
        }
        z_out[row0 + tid] = (float)fk;
        s_idx[tid] = fk;
    }
    __syncthreads();

    // ---- q gather: bit-exact codebook rows, coalesced float4 stores ----
    const float4* cb4 = (const float4*)cb;
    float4* q4 = (float4*)q_out;
#pragma unroll
    for (int it = 0; it < 8; ++it) {
        const int slot = it * BLOCK + tid;    // 0..2047
        const int rl   = slot >> 4;           // row 0..127
        const int c4   = slot & 15;
        q4[(size_t)(row0 + rl) * 16 + c4] = cb4[s_idx[rl] * 16 + c4];
    }
}

extern "C" void kernel_launch(void* const* d_in, const int* in_sizes, int n_in,
                              void* d_out, int out_size, void* d_ws, size_t ws_size,
                              hipStream_t stream) {
    const float* h  = (const float*)d_in[0];
    const float* cb = (const float*)d_in[1];
    float* out   = (float*)d_out;
    float* z_out = out;              // 131072 floats
    float* q_out = out + N_ROWS;     // 131072*64 floats
    (void)d_ws; (void)ws_size;

    vq_main<<<dim3(N_ROWS / ROWS_PB), dim3(BLOCK), 0, stream>>>(h, cb, z_out, q_out);
}